// Round 1
// baseline (439.578 us; speedup 1.0000x reference)
//
#include <hip/hip_runtime.h>
#include <hip/hip_bf16.h>
#include <stdint.h>

typedef __attribute__((ext_vector_type(8))) short short8;
typedef __attribute__((ext_vector_type(4))) float f32x4;
typedef __attribute__((ext_vector_type(4))) unsigned int uint4v;

#define KKTOT 4096   // reduction length = K*E
#define NTILES 64    // K-steps of 64
#define BM 64
#define BK 64
#define NN 256

typedef const __attribute__((address_space(1))) unsigned int* gas_ptr;
typedef __attribute__((address_space(3))) unsigned int* las_ptr;

__device__ __forceinline__ void gload_lds16(const void* g, void* l) {
  __builtin_amdgcn_global_load_lds((gas_ptr)g, (las_ptr)l, 16, 0, 0);
}

__device__ __forceinline__ unsigned pack_bf2(float a, float b) {
  __hip_bfloat162 h = __float22bfloat162_rn(make_float2(a, b));
  union { __hip_bfloat162 h2; unsigned u; } cv; cv.h2 = h;
  return cv.u;
}

// ---------------- pack W1/W2 -> bf16, interleaved + bank-swizzle baked ------
// WB[kt][n][j'] : n even -> W1[c=n>>1], n odd -> W2[c=n>>1]; kk = kt*64+j,
// k = kk>>3, e = kk&7 ; j' = j ^ ((n&7)<<3)  (st-style 16B-slot XOR swizzle)
__global__ void pack_w(const float* __restrict__ W1, const float* __restrict__ W2,
                       __hip_bfloat16* __restrict__ WB) {
  int idx = blockIdx.x * 256 + threadIdx.x;   // 64*256*64 = 1<<20 total
  int j  = idx & 63;
  int n  = (idx >> 6) & 255;
  int kt = idx >> 14;
  int c  = n >> 1;
  const float* W = (n & 1) ? W2 : W1;
  int kk = kt * 64 + j;
  int k = kk >> 3, e = kk & 7;
  float v = W[(c * 8 + e) * 512 + k];
  WB[(size_t)kt * 16384 + n * 64 + (j ^ ((n & 7) << 3))] = __float2bfloat16(v);
}

// ---------------- main GEMM + gate + per-block max --------------------------
__global__ __launch_bounds__(512, 2) void gemm_gate(
    const float* __restrict__ z, const __hip_bfloat16* __restrict__ WB,
    const float* __restrict__ b1, const float* __restrict__ b2,
    float* __restrict__ partial) {
  __shared__ __align__(16) __hip_bfloat16 As[2][BM * BK];   // 2 x 8 KB
  __shared__ __align__(16) __hip_bfloat16 Bs[2][NN * BK];   // 2 x 32 KB

  const int t = threadIdx.x;
  const int l = t & 63;
  const int w = t >> 6;          // 8 waves: wm = w>>2 (M half), wn = w&3 (N quarter)
  const int wm = w >> 2;
  const int wn = w & 3;
  const int kgrp = l >> 4;       // 0..3
  const int lrow = l & 15;
  const int bid = blockIdx.x;
  const size_t m0 = (size_t)bid * BM;

  // A staging assignment: thread -> (row, 8-float segment)
  const int arow = t >> 3;       // 0..63
  const int aseg = t & 7;        // 0..7
  const float* asrc_base = z + (m0 + arow) * (size_t)KKTOT + aseg * 8;
  const int aoff = arow * 128 + ((aseg ^ (arow & 7)) << 4);  // swizzled LDS byte off

  f32x4 acc[2][4];
#pragma unroll
  for (int i = 0; i < 2; ++i)
#pragma unroll
    for (int j = 0; j < 4; ++j) acc[i][j] = (f32x4)0.0f;

  // ---- prologue: stage tile 0
  {
    const float4 f0 = *(const float4*)(asrc_base);
    const float4 f1 = *(const float4*)(asrc_base + 4);
    uint4v pk;
    pk.x = pack_bf2(f0.x, f0.y); pk.y = pack_bf2(f0.z, f0.w);
    pk.z = pack_bf2(f1.x, f1.y); pk.w = pack_bf2(f1.z, f1.w);
    *(uint4v*)((char*)&As[0][0] + aoff) = pk;
    const char* gsrc = (const char*)WB;
#pragma unroll
    for (int r = 0; r < 4; ++r) {
      int o = t * 16 + r * 8192;
      gload_lds16(gsrc + o, (char*)&Bs[0][0] + o);
    }
  }
  __syncthreads();

  for (int kt = 0; kt < NTILES; ++kt) {
    const int cur = kt & 1;
    const bool has_next = (kt + 1 < NTILES);
    float4 f0, f1;
    if (has_next) {
      // T14: issue next-tile loads EARLY (A to regs, B direct to LDS), write A late
      const float* s = asrc_base + (size_t)(kt + 1) * BK;
      f0 = *(const float4*)(s);
      f1 = *(const float4*)(s + 4);
      const char* gsrc = (const char*)WB + (size_t)(kt + 1) * 32768;
      char* bdst = (char*)&Bs[cur ^ 1][0];
#pragma unroll
      for (int r = 0; r < 4; ++r) {
        int o = t * 16 + r * 8192;
        gload_lds16(gsrc + o, bdst + o);
      }
    }
    // ---- compute current tile
    const char* abase = (const char*)&As[cur][0];
    const char* bbase = (const char*)&Bs[cur][0];
    short8 af[2][2], bfr[4][2];
#pragma unroll
    for (int i = 0; i < 2; ++i) {
      const int r = wm * 32 + i * 16 + lrow;
      const int sw = (r & 7) << 4;
#pragma unroll
      for (int h = 0; h < 2; ++h)
        af[i][h] = *(const short8*)(abase + r * 128 + (((h * 4 + kgrp) << 4) ^ sw));
    }
#pragma unroll
    for (int j = 0; j < 4; ++j) {
      const int r = wn * 64 + j * 16 + lrow;
      const int sw = (r & 7) << 4;
#pragma unroll
      for (int h = 0; h < 2; ++h)
        bfr[j][h] = *(const short8*)(bbase + r * 128 + (((h * 4 + kgrp) << 4) ^ sw));
    }
#pragma unroll
    for (int i = 0; i < 2; ++i)
#pragma unroll
      for (int j = 0; j < 4; ++j)
#pragma unroll
        for (int h = 0; h < 2; ++h)
          acc[i][j] = __builtin_amdgcn_mfma_f32_16x16x32_bf16(
              af[i][h], bfr[j][h], acc[i][j], 0, 0, 0);
    if (has_next) {
      uint4v pk;
      pk.x = pack_bf2(f0.x, f0.y); pk.y = pack_bf2(f0.z, f0.w);
      pk.z = pack_bf2(f1.x, f1.y); pk.w = pack_bf2(f1.z, f1.w);
      *(uint4v*)((char*)&As[cur ^ 1][0] + aoff) = pk;
    }
    __syncthreads();
  }

  // ---- epilogue: gate + max over this block's 32 rows (per wave-half)
  // C layout (m89): col = lane&15 (= n within frag), row = (lane>>4)*4 + reg
  const int col = lrow;
  float gmax[4];
#pragma unroll
  for (int j = 0; j < 4; ++j) {
    const int c = wn * 32 + j * 8 + (col >> 1);
    const float vb1 = b1[c], vb2 = b2[c];
    float gm = -3.4e38f;
#pragma unroll
    for (int i = 0; i < 2; ++i) {
#pragma unroll
      for (int rr = 0; rr < 4; ++rr) {
        float v = acc[i][j][rr];
        float p = __shfl_xor(v, 1, 64);           // partner conv value, same row
        float c1 = (col & 1) ? p : v;
        float c2 = (col & 1) ? v : p;
        c1 += vb1; c2 += vb2;
        float g = c1 * (1.0f / (1.0f + __expf(-c2)));
        gm = fmaxf(gm, g);
      }
    }
    gm = fmaxf(gm, __shfl_xor(gm, 16, 64));       // combine the 4 row-groups
    gm = fmaxf(gm, __shfl_xor(gm, 32, 64));
    gmax[j] = gm;
  }
  if ((l & 1) == 0 && l < 16) {
    float* pp = partial + ((size_t)bid * 2 + wm) * 128;
#pragma unroll
    for (int j = 0; j < 4; ++j)
      pp[wn * 32 + j * 8 + (l >> 1)] = gmax[j];
  }
}

// ---------------- final reduction over 64 partials per (b,c) ----------------
__global__ void reduce_max(const float* __restrict__ partial, float* __restrict__ out) {
  int idx = blockIdx.x * 256 + threadIdx.x;   // 1024 total
  if (idx >= 1024) return;
  int b = idx >> 7, c = idx & 127;
  float m = -3.4e38f;
#pragma unroll 8
  for (int p = 0; p < 64; ++p)
    m = fmaxf(m, partial[(size_t)(b * 64 + p) * 128 + c]);
  out[idx] = m;
}

extern "C" void kernel_launch(void* const* d_in, const int* in_sizes, int n_in,
                              void* d_out, int out_size, void* d_ws, size_t ws_size,
                              hipStream_t stream) {
  const float* z  = (const float*)d_in[0];
  const float* W1 = (const float*)d_in[1];
  const float* b1 = (const float*)d_in[2];
  const float* W2 = (const float*)d_in[3];
  const float* b2 = (const float*)d_in[4];
  float* out = (float*)d_out;

  __hip_bfloat16* WB = (__hip_bfloat16*)d_ws;                    // 2 MB
  float* partial = (float*)((char*)d_ws + 2 * 1024 * 1024);      // 256 KB

  pack_w<<<4096, 256, 0, stream>>>(W1, W2, WB);
  gemm_gate<<<256, 512, 0, stream>>>(z, WB, b1, b2, partial);
  reduce_max<<<4, 256, 0, stream>>>(partial, out);
}